// Round 7
// baseline (274.818 us; speedup 1.0000x reference)
//
#include <hip/hip_runtime.h>
#include <math.h>

#define B_ 8
#define S_ 2048
#define D_ 128
#define K_ 64
#define SIG_ 0.5f
#define EPS_ 10.0f
#define E_ 2.718281828459045f

// XCD-aware work remap (bijective on [0,512)): batch = bx&7 == XCD id.
__device__ __forceinline__ int remap512(int bx) {
    return ((bx & 7) << 6) | (bx >> 3);
}

// ---------------- K1: per (b,k) class stats, 4-wave ballot + immediate gather
__global__ void __launch_bounds__(256) k1_stats(
    const float* __restrict__ F, const int* __restrict__ L,
    float* __restrict__ fsumK, float* __restrict__ ssumK, float* __restrict__ cntK,
    int* __restrict__ counter) {
    int bx = remap512(blockIdx.x);
    int k = bx & (K_ - 1);
    int b = bx >> 6;
    int tid = threadIdx.x;
    int lane = tid & 63;
    int wv = tid >> 6;

    __shared__ float redF[4][128];
    __shared__ float redS[4];
    __shared__ int   redC[4];

    const int* Lb = L + b * S_;
    const float* Fb = F + (size_t)b * S_ * D_;

    float a0 = 0.f, a1 = 0.f, q0 = 0.f, q1 = 0.f;
    int cnt = 0;
    #pragma unroll
    for (int rr = 0; rr < 8; ++rr) {
        int r = (wv << 3) + rr;
        int lbl = Lb[(r << 6) + lane];
        unsigned long long m = __ballot(lbl == k);
        cnt += (int)__popcll(m);
        while (m) {               // wave-uniform trip count (~1 per round)
            int i = __ffsll((long long)m) - 1;
            m &= m - 1;
            const float* row = Fb + (size_t)((r << 6) + i) * D_;
            float v0 = row[lane];          // lane-indexed -> vector loads
            float v1 = row[64 + lane];
            a0 += v0; q0 = fmaf(v0, v0, q0);
            a1 += v1; q1 = fmaf(v1, v1, q1);
        }
    }
    float qq = q0 + q1;
    #pragma unroll
    for (int m = 1; m < 64; m <<= 1) qq += __shfl_xor(qq, m);
    redF[wv][lane] = a0;
    redF[wv][64 + lane] = a1;
    if (lane == 0) { redS[wv] = qq; redC[wv] = cnt; }
    __syncthreads();

    if (tid < 128) {
        float s = (redF[0][tid] + redF[1][tid]) + (redF[2][tid] + redF[3][tid]);
        fsumK[(size_t)bx * D_ + tid] = s;
    }
    if (tid == 0) {
        ssumK[bx] = (redS[0] + redS[1]) + (redS[2] + redS[3]);
        cntK[bx] = (float)(redC[0] + redC[1] + redC[2] + redC[3]);
        if (bx == 0) *counter = 0;   // stream-ordered init for k3's last-block reduce
    }
}

// ---------------- K3: main per-anchor kernel + last-block final reduce
__global__ void __launch_bounds__(256, 2) k3_main(
    const float* __restrict__ F, const float* __restrict__ C,
    const float* __restrict__ phi, const int* __restrict__ L,
    const float* __restrict__ fsumK, const float* __restrict__ ssumK,
    const float* __restrict__ cntK, float* __restrict__ partial,
    int* __restrict__ counter, float* __restrict__ out) {

    __shared__ float Cs[K_ * 129];   // 129 stride: 2 lanes/bank on b32 = free
    __shared__ float4 redA[256];
    __shared__ float Fa[D_];
    __shared__ float wacc[4];
    __shared__ int isLast;
    int tid = threadIdx.x;
    int bxw = remap512(blockIdx.x);
    int b = bxw >> 6;

    // stage centroids: float4 global loads, scalar LDS stores into padded rows
    {
        const float4* C4 = (const float4*)C;
        #pragma unroll
        for (int it = 0; it < 8; ++it) {
            int i = it * 256 + tid;
            float4 v = C4[i];
            float* p = &Cs[(i >> 5) * 129 + ((i & 31) << 2)];
            p[0] = v.x; p[1] = v.y; p[2] = v.z; p[3] = v.w;
        }
    }
    // Fa[d] = sum_k fsumK[b,k,d]
    {
        int d4 = tid & 31, kg = tid >> 5;
        const float4* g4 = (const float4*)(fsumK + (size_t)b * K_ * D_) + (size_t)kg * 8 * 32 + d4;
        float4 s; s.x = s.y = s.z = s.w = 0.f;
        #pragma unroll
        for (int kk = 0; kk < 8; ++kk) {
            float4 v = g4[(size_t)kk * 32];
            s.x += v.x; s.y += v.y; s.z += v.z; s.w += v.w;
        }
        redA[tid] = s;
    }
    __syncthreads();
    if (tid < 32) {
        float4 a; a.x = a.y = a.z = a.w = 0.f;
        #pragma unroll
        for (int g = 0; g < 8; ++g) {
            float4 v = redA[g * 32 + tid];
            a.x += v.x; a.y += v.y; a.z += v.z; a.w += v.w;
        }
        ((float4*)Fa)[tid] = a;
    }
    __syncthreads();

    int lane = tid & 63;
    int wv = tid >> 6;

    float c0 = 0.f, c1 = 0.f, c2 = 0.f, c3 = 0.f;
    #pragma unroll
    for (int dd = 0; dd < D_; dd += 4) {
        c0 = fmaf(Cs[lane * 129 + dd + 0], Cs[lane * 129 + dd + 0], c0);
        c1 = fmaf(Cs[lane * 129 + dd + 1], Cs[lane * 129 + dd + 1], c1);
        c2 = fmaf(Cs[lane * 129 + dd + 2], Cs[lane * 129 + dd + 2], c2);
        c3 = fmaf(Cs[lane * 129 + dd + 3], Cs[lane * 129 + dd + 3], c3);
    }
    float csq = (c0 + c1) + (c2 + c3);
    float phv = phi[lane];
    float ssl = ssumK[b * K_ + lane];
    float cnl = cntK[b * K_ + lane];
    float ssA = ssl;
    #pragma unroll
    for (int m = 1; m < 64; m <<= 1) ssA += __shfl_xor(ssA, m);

    int wid = __builtin_amdgcn_readfirstlane(tid) >> 6;
    int o = bxw * 4 + wid;
    int a0g = o * 8;
    const float4* F4 = (const float4*)F;

    // ---- phase A: per-anchor sq / dot(fsumK[lbl]) / dot(Fa); 8 lanes/anchor
    int j_of = lane >> 3, q = lane & 7;
    int a_mine = a0g + j_of;
    int lbl_p = L[a_mine];
    const float4* fr = F4 + (size_t)a_mine * 32;
    const float4* fk = (const float4*)(fsumK + (size_t)(b * K_ + lbl_p) * D_);
    const float4* fa4 = (const float4*)Fa;

    float sq_p = 0.f, dk_p = 0.f, da_p = 0.f;
    #pragma unroll
    for (int i = 0; i < 4; ++i) {
        int dq = i * 8 + q;
        float4 fv = fr[dq];
        float4 kv = fk[dq];
        float4 av = fa4[dq];
        sq_p = fmaf(fv.x, fv.x, fmaf(fv.y, fv.y, fmaf(fv.z, fv.z, fmaf(fv.w, fv.w, sq_p))));
        dk_p = fmaf(fv.x, kv.x, fmaf(fv.y, kv.y, fmaf(fv.z, kv.z, fmaf(fv.w, kv.w, dk_p))));
        da_p = fmaf(fv.x, av.x, fmaf(fv.y, av.y, fmaf(fv.z, av.z, fmaf(fv.w, av.w, da_p))));
    }
    #pragma unroll
    for (int m = 1; m < 8; m <<= 1) {
        sq_p += __shfl_xor(sq_p, m);
        dk_p += __shfl_xor(dk_p, m);
        da_p += __shfl_xor(da_p, m);
    }

    // ---- phase B: centroid dots, lane = k.
    // CRITICAL: force the anchor base into a VGPR so the F loads are emitted
    // as vector global_load_dwordx4 (vmcnt, in-order, pipelineable) instead of
    // wave-uniform s_load (SMEM shares lgkmcnt with ds_read and completes
    // OUT-OF-ORDER -> every Cs ds_read use forces lgkmcnt(0), draining all
    // in-flight s_loads at L2 latency each iteration).
    int a0v = a0g;
    asm volatile("" : "+v"(a0v));
    const float4* pj[8];
    #pragma unroll
    for (int j = 0; j < 8; ++j) pj[j] = F4 + (size_t)(a0v + j) * 32;

    float facc[8];
    #pragma unroll
    for (int j = 0; j < 8; ++j) facc[j] = 0.f;

    #pragma unroll
    for (int dq = 0; dq < 32; ++dq) {
        float4 fb[8];
        #pragma unroll
        for (int j = 0; j < 8; ++j) fb[j] = pj[j][dq];   // imm-offset vector loads
        int cbase = lane * 129 + (dq << 2);
        float cv0 = Cs[cbase + 0];
        float cv1 = Cs[cbase + 1];
        float cv2 = Cs[cbase + 2];
        float cv3 = Cs[cbase + 3];
        #pragma unroll
        for (int j = 0; j < 8; ++j) {
            facc[j] = fmaf(fb[j].x, cv0,
                      fmaf(fb[j].y, cv1,
                      fmaf(fb[j].z, cv2,
                      fmaf(fb[j].w, cv3, facc[j]))));
        }
    }

    // ---- phase C: per-anchor scalar epilogue
    float acc = 0.f;
    #pragma unroll
    for (int j = 0; j < 8; ++j) {
        float sq_j = __shfl(sq_p, j * 8);
        float dk_j = __shfl(dk_p, j * 8);
        float da_j = __shfl(da_p, j * 8);
        int lbl_j = __shfl(lbl_p, j * 8);
        float cnt_j = __shfl(cnl, lbl_j);
        float ssm_j = __shfl(ssl, lbl_j);

        float cd2 = (sq_j + csq - 2.f * facc[j]) * (1.f / D_);
        cd2 = fmaxf(cd2, 0.f) / phv;

        float s_cd = cd2;
        #pragma unroll
        for (int m = 1; m < 64; m <<= 1) s_cd += __shfl_xor(s_cd, m);
        float pos_cent = __shfl(cd2, lbl_j);

        float ncx = (s_cd - pos_cent) * (1.f / (K_ - 1));
        float S_same = (cnt_j * sq_j + ssm_j - 2.f * dk_j) * (1.f / D_);
        float S_all = ((float)S_ * sq_j + ssA - 2.f * da_j) * (1.f / D_);
        float pos_x = fmaxf(S_same, 0.f) / fmaxf(cnt_j - 1.f, 1.f);
        float neg_cnt = (float)S_ - cnt_j;
        float neg_x = fmaxf(S_all - S_same, 0.f) / fmaxf(neg_cnt, 1.f);

        float neg_sup = neg_x * __logf(neg_x + E_);
        float ncl = ncx * __logf(ncx + E_);

        float pa = SIG_ * pos_x + (1.f - SIG_) * pos_cent
                 - (SIG_ * neg_sup + (1.f - SIG_) * ncl) + EPS_;
        if (neg_cnt > 0.5f) acc += pa;
    }

    if (lane == 0) wacc[wid] = acc;
    __syncthreads();

    // ---- last-block final reduce (agent-scope atomics; proven)
    if (tid == 0) {
        float blk = wacc[0] + wacc[1] + wacc[2] + wacc[3];
        __hip_atomic_store(&partial[bxw], blk, __ATOMIC_RELAXED,
                           __HIP_MEMORY_SCOPE_AGENT);
        int old = __hip_atomic_fetch_add(counter, 1, __ATOMIC_ACQ_REL,
                                         __HIP_MEMORY_SCOPE_AGENT);
        isLast = (old == (int)gridDim.x - 1) ? 1 : 0;
    }
    __syncthreads();
    if (isLast) {
        float v = 0.f;
        for (int i = tid; i < 512; i += 256) {
            v += __hip_atomic_load(&partial[i], __ATOMIC_RELAXED,
                                   __HIP_MEMORY_SCOPE_AGENT);
        }
        #pragma unroll
        for (int m = 1; m < 64; m <<= 1) v += __shfl_xor(v, m);
        if (lane == 0) wacc[wv] = v;
        __syncthreads();
        if (tid == 0) out[0] = (wacc[0] + wacc[1] + wacc[2] + wacc[3]) * (1.0f / (float)S_);
    }
}

extern "C" void kernel_launch(void* const* d_in, const int* in_sizes, int n_in,
                              void* d_out, int out_size, void* d_ws, size_t ws_size,
                              hipStream_t stream) {
    const float* F = (const float*)d_in[0];    // [B,S,D]
    const float* C = (const float*)d_in[1];    // [K,D]
    const float* phi = (const float*)d_in[2];  // [K]
    const int* L = (const int*)d_in[3];        // [B,S]
    float* out = (float*)d_out;

    float* ws = (float*)d_ws;
    float* fsumK = ws;                                // B*K*D = 65536
    float* ssumK = fsumK + (size_t)B_ * K_ * D_;      // 512
    float* cntK  = ssumK + B_ * K_;                   // 512
    float* partial = cntK + B_ * K_;                  // 512
    int* counter = (int*)(partial + 512);             // 1

    k1_stats<<<B_ * K_, 256, 0, stream>>>(F, L, fsumK, ssumK, cntK, counter);
    k3_main<<<512, 256, 0, stream>>>(F, C, phi, L, fsumK, ssumK, cntK, partial, counter, out);
}

// Round 8
// 39.681 us; speedup vs baseline: 6.9257x; 6.9257x over previous
//
#include <hip/hip_runtime.h>
#include <math.h>

#define B_ 8
#define S_ 2048
#define D_ 128
#define K_ 64
#define SIG_ 0.5f
#define EPS_ 10.0f
#define E_ 2.718281828459045f

#define AL(p) __hip_atomic_load((p), __ATOMIC_RELAXED, __HIP_MEMORY_SCOPE_AGENT)
#define AS(p, v) __hip_atomic_store((p), (v), __ATOMIC_RELAXED, __HIP_MEMORY_SCOPE_AGENT)

// XCD-aware work remaps (HW round-robins blockIdx over 8 XCDs; batch == XCD).
__device__ __forceinline__ int remap512(int bx)  { return ((bx & 7) << 6) | (bx >> 3); }
__device__ __forceinline__ int remap1024(int bx) { return ((bx & 7) << 7) | (bx >> 3); }

// ---------------- K1: per (b,k) class stats, 4-wave ballot + immediate gather
// grid = B*K = 512 blocks, 256 threads. Also: b==0 blocks write csqK[k];
// block 0 zeroes the finish-counter tree for k3.
__global__ void __launch_bounds__(256) k1_stats(
    const float* __restrict__ F, const float* __restrict__ C,
    const int* __restrict__ L,
    float* __restrict__ fsumK, float* __restrict__ ssumK, float* __restrict__ cntK,
    float* __restrict__ csqK, int* __restrict__ cnts) {
    int bx = remap512(blockIdx.x);
    int k = bx & (K_ - 1);
    int b = bx >> 6;
    int tid = threadIdx.x;
    int lane = tid & 63;
    int wv = tid >> 6;

    __shared__ float redF[4][128];
    __shared__ float redS[4];
    __shared__ int   redC[4];

    const int* Lb = L + b * S_;
    const float* Fb = F + (size_t)b * S_ * D_;

    float a0 = 0.f, a1 = 0.f, q0 = 0.f, q1 = 0.f;
    int cnt = 0;
    #pragma unroll
    for (int rr = 0; rr < 8; ++rr) {
        int r = (wv << 3) + rr;
        int lbl = Lb[(r << 6) + lane];
        unsigned long long m = __ballot(lbl == k);
        cnt += (int)__popcll(m);
        while (m) {               // wave-uniform trip count (~1 per round)
            int i = __ffsll((long long)m) - 1;
            m &= m - 1;
            const float* row = Fb + (size_t)((r << 6) + i) * D_;
            float v0 = row[lane];          // lane-indexed -> vector loads
            float v1 = row[64 + lane];
            a0 += v0; q0 = fmaf(v0, v0, q0);
            a1 += v1; q1 = fmaf(v1, v1, q1);
        }
    }
    float qq = q0 + q1;
    #pragma unroll
    for (int m = 1; m < 64; m <<= 1) qq += __shfl_xor(qq, m);
    redF[wv][lane] = a0;
    redF[wv][64 + lane] = a1;
    if (lane == 0) { redS[wv] = qq; redC[wv] = cnt; }
    __syncthreads();

    if (tid < 128) {
        float s = (redF[0][tid] + redF[1][tid]) + (redF[2][tid] + redF[3][tid]);
        fsumK[(size_t)bx * D_ + tid] = s;
    }
    if (tid == 0) {
        ssumK[bx] = (redS[0] + redS[1]) + (redS[2] + redS[3]);
        cntK[bx] = (float)(redC[0] + redC[1] + redC[2] + redC[3]);
    }
    // csqK[k] computed once (b==0 slice), wave 0
    if (b == 0 && wv == 0) {
        float x0 = C[(k << 7) + lane];
        float x1 = C[(k << 7) + 64 + lane];
        float cs = fmaf(x0, x0, x1 * x1);
        #pragma unroll
        for (int m = 1; m < 64; m <<= 1) cs += __shfl_xor(cs, m);
        if (lane == 0) csqK[k] = cs;
    }
    // zero finish-counter tree (16 leaves at stride 16 + root at [256])
    if (blockIdx.x == 0 && tid < 17) AS(&cnts[tid * 16], 0);
}

// ---------------- K3: main per-anchor kernel + tree-counter final reduce
// grid = 1024 blocks x 256 threads; each wave handles 4 anchors.
__global__ void __launch_bounds__(256) k3_main(
    const float* __restrict__ F, const float* __restrict__ C,
    const float* __restrict__ phi, const int* __restrict__ L,
    const float* __restrict__ fsumK, const float* __restrict__ ssumK,
    const float* __restrict__ cntK, const float* __restrict__ csqK,
    float* __restrict__ partial, int* __restrict__ cnts,
    float* __restrict__ out) {

    __shared__ float Cs[K_ * 129];   // 129 stride: conflict-free b32 column reads
    __shared__ float4 redA[256];
    __shared__ float Fa[D_];
    __shared__ float wacc[4];
    __shared__ int isLast;
    int tid = threadIdx.x;
    int bw = remap1024(blockIdx.x);
    int b = bw >> 7;                 // 128 blocks per batch; == blockIdx.x & 7

    // stage centroids: float4 global loads, scalar LDS stores into padded rows
    {
        const float4* C4 = (const float4*)C;
        #pragma unroll
        for (int it = 0; it < 8; ++it) {
            int i = it * 256 + tid;
            float4 v = C4[i];
            float* p = &Cs[(i >> 5) * 129 + ((i & 31) << 2)];
            p[0] = v.x; p[1] = v.y; p[2] = v.z; p[3] = v.w;
        }
    }
    // Fa[d] = sum_k fsumK[b,k,d]
    {
        int d4 = tid & 31, kg = tid >> 5;
        const float4* g4 = (const float4*)(fsumK + (size_t)b * K_ * D_) + (size_t)kg * 8 * 32 + d4;
        float4 s; s.x = s.y = s.z = s.w = 0.f;
        #pragma unroll
        for (int kk = 0; kk < 8; ++kk) {
            float4 v = g4[(size_t)kk * 32];
            s.x += v.x; s.y += v.y; s.z += v.z; s.w += v.w;
        }
        redA[tid] = s;
    }
    __syncthreads();
    if (tid < 32) {
        float4 a; a.x = a.y = a.z = a.w = 0.f;
        #pragma unroll
        for (int g = 0; g < 8; ++g) {
            float4 v = redA[g * 32 + tid];
            a.x += v.x; a.y += v.y; a.z += v.z; a.w += v.w;
        }
        ((float4*)Fa)[tid] = a;
    }
    __syncthreads();

    int lane = tid & 63;
    int wv = tid >> 6;

    float csq = csqK[lane];          // precomputed in k1
    float phv = phi[lane];
    float ssl = ssumK[b * K_ + lane];
    float cnl = cntK[b * K_ + lane];
    float ssA = ssl;
    #pragma unroll
    for (int m = 1; m < 64; m <<= 1) ssA += __shfl_xor(ssA, m);

    int wid = __builtin_amdgcn_readfirstlane(tid) >> 6;   // SGPR wave id
    int a0g = bw * 16 + wid * 4;     // this wave's 4 anchors
    const float4* F4 = (const float4*)F;

    // ---- phase A: per-anchor sq / dot(fsumK[lbl]) / dot(Fa); 16 lanes/anchor
    int j_of = lane >> 4, q = lane & 15;
    int a_mine = a0g + j_of;
    int lbl_p = L[a_mine];
    const float4* fr = F4 + (size_t)a_mine * 32;
    const float4* fk = (const float4*)(fsumK + (size_t)(b * K_ + lbl_p) * D_);
    const float4* fa4 = (const float4*)Fa;

    float sq_p = 0.f, dk_p = 0.f, da_p = 0.f;
    #pragma unroll
    for (int i = 0; i < 2; ++i) {
        int dq = i * 16 + q;
        float4 fv = fr[dq];
        float4 kv = fk[dq];
        float4 av = fa4[dq];
        sq_p = fmaf(fv.x, fv.x, fmaf(fv.y, fv.y, fmaf(fv.z, fv.z, fmaf(fv.w, fv.w, sq_p))));
        dk_p = fmaf(fv.x, kv.x, fmaf(fv.y, kv.y, fmaf(fv.z, kv.z, fmaf(fv.w, kv.w, dk_p))));
        da_p = fmaf(fv.x, av.x, fmaf(fv.y, av.y, fmaf(fv.z, av.z, fmaf(fv.w, av.w, da_p))));
    }
    #pragma unroll
    for (int m = 1; m < 16; m <<= 1) {
        sq_p += __shfl_xor(sq_p, m);
        dk_p += __shfl_xor(dk_p, m);
        da_p += __shfl_xor(da_p, m);
    }

    // ---- phase B: centroid dots, lane = k, wave-uniform feature loads (s_load)
    float facc[4];
    #pragma unroll
    for (int j = 0; j < 4; ++j) facc[j] = 0.f;

    for (int dq = 0; dq < 32; ++dq) {
        float4 fw[4];
        #pragma unroll
        for (int j = 0; j < 4; ++j) fw[j] = F4[(size_t)(a0g + j) * 32 + dq];
        int cbase = lane * 129 + (dq << 2);
        float cv0 = Cs[cbase + 0];
        float cv1 = Cs[cbase + 1];
        float cv2 = Cs[cbase + 2];
        float cv3 = Cs[cbase + 3];
        #pragma unroll
        for (int j = 0; j < 4; ++j) {
            facc[j] = fmaf(fw[j].x, cv0,
                      fmaf(fw[j].y, cv1,
                      fmaf(fw[j].z, cv2,
                      fmaf(fw[j].w, cv3, facc[j]))));
        }
    }

    // ---- phase C: per-anchor scalar epilogue (4 anchors/wave)
    float acc = 0.f;
    #pragma unroll
    for (int j = 0; j < 4; ++j) {
        float sq_j = __shfl(sq_p, j * 16);
        float dk_j = __shfl(dk_p, j * 16);
        float da_j = __shfl(da_p, j * 16);
        int lbl_j = __shfl(lbl_p, j * 16);
        float cnt_j = __shfl(cnl, lbl_j);
        float ssm_j = __shfl(ssl, lbl_j);

        float cd2 = (sq_j + csq - 2.f * facc[j]) * (1.f / D_);
        cd2 = fmaxf(cd2, 0.f) / phv;

        float s_cd = cd2;
        #pragma unroll
        for (int m = 1; m < 64; m <<= 1) s_cd += __shfl_xor(s_cd, m);
        float pos_cent = __shfl(cd2, lbl_j);

        float ncx = (s_cd - pos_cent) * (1.f / (K_ - 1));
        float S_same = (cnt_j * sq_j + ssm_j - 2.f * dk_j) * (1.f / D_);
        float S_all = ((float)S_ * sq_j + ssA - 2.f * da_j) * (1.f / D_);
        float pos_x = fmaxf(S_same, 0.f) / fmaxf(cnt_j - 1.f, 1.f);
        float neg_cnt = (float)S_ - cnt_j;
        float neg_x = fmaxf(S_all - S_same, 0.f) / fmaxf(neg_cnt, 1.f);

        float neg_sup = neg_x * __logf(neg_x + E_);
        float ncl = ncx * __logf(ncx + E_);

        float pa = SIG_ * pos_x + (1.f - SIG_) * pos_cent
                 - (SIG_ * neg_sup + (1.f - SIG_) * ncl) + EPS_;
        if (neg_cnt > 0.5f) acc += pa;
    }

    if (lane == 0) wacc[wid] = acc;
    __syncthreads();

    // ---- tree finish counter: 16 cacheline-spaced leaves + root
    if (tid == 0) {
        float blk = wacc[0] + wacc[1] + wacc[2] + wacc[3];
        AS(&partial[bw], blk);
        int leaf = bw & 15;
        int old = __hip_atomic_fetch_add(&cnts[leaf * 16], 1, __ATOMIC_ACQ_REL,
                                         __HIP_MEMORY_SCOPE_AGENT);
        int fin = 0;
        if (old == 64 - 1) {      // 1024 blocks / 16 leaves
            int r = __hip_atomic_fetch_add(&cnts[256], 1, __ATOMIC_ACQ_REL,
                                           __HIP_MEMORY_SCOPE_AGENT);
            fin = (r == 15);
        }
        isLast = fin;
    }
    __syncthreads();
    if (isLast) {
        float v = 0.f;
        for (int i = tid; i < 1024; i += 256) v += AL(&partial[i]);
        #pragma unroll
        for (int m = 1; m < 64; m <<= 1) v += __shfl_xor(v, m);
        if (lane == 0) wacc[wv] = v;
        __syncthreads();
        if (tid == 0) out[0] = (wacc[0] + wacc[1] + wacc[2] + wacc[3]) * (1.0f / (float)S_);
    }
}

extern "C" void kernel_launch(void* const* d_in, const int* in_sizes, int n_in,
                              void* d_out, int out_size, void* d_ws, size_t ws_size,
                              hipStream_t stream) {
    const float* F = (const float*)d_in[0];    // [B,S,D]
    const float* C = (const float*)d_in[1];    // [K,D]
    const float* phi = (const float*)d_in[2];  // [K]
    const int* L = (const int*)d_in[3];        // [B,S]
    float* out = (float*)d_out;

    float* ws = (float*)d_ws;
    float* fsumK = ws;                                // B*K*D = 65536
    float* ssumK = fsumK + (size_t)B_ * K_ * D_;      // 512
    float* cntK  = ssumK + B_ * K_;                   // 512
    float* csqK  = cntK + B_ * K_;                    // 64
    float* partial = csqK + K_;                       // 1024
    int* cnts = (int*)(partial + 1024);               // 512 ints (tree)

    k1_stats<<<B_ * K_, 256, 0, stream>>>(F, C, L, fsumK, ssumK, cntK, csqK, cnts);
    k3_main<<<1024, 256, 0, stream>>>(F, C, phi, L, fsumK, ssumK, cntK, csqK,
                                      partial, cnts, out);
}

// Round 9
// 39.239 us; speedup vs baseline: 7.0037x; 1.0113x over previous
//
#include <hip/hip_runtime.h>
#include <math.h>

#define B_ 8
#define S_ 2048
#define D_ 128
#define K_ 64
#define SIG_ 0.5f
#define EPS_ 10.0f
#define E_ 2.718281828459045f

#define AL(p) __hip_atomic_load((p), __ATOMIC_RELAXED, __HIP_MEMORY_SCOPE_AGENT)
#define AS(p, v) __hip_atomic_store((p), (v), __ATOMIC_RELAXED, __HIP_MEMORY_SCOPE_AGENT)

// XCD-aware work remap (bijective on [0,512)): batch = bx&7 == XCD id.
__device__ __forceinline__ int remap512(int bx) { return ((bx & 7) << 6) | (bx >> 3); }

// ---------------- K1: per (b,k) class stats, 4-wave ballot + immediate gather
// grid = B*K = 512 blocks, 256 threads. b==0 blocks also write csqK[k];
// block 0 zeroes k3's finish-counter tree.
__global__ void __launch_bounds__(256) k1_stats(
    const float* __restrict__ F, const float* __restrict__ C,
    const int* __restrict__ L,
    float* __restrict__ fsumK, float* __restrict__ ssumK, float* __restrict__ cntK,
    float* __restrict__ csqK, int* __restrict__ cnts) {
    int bx = remap512(blockIdx.x);
    int k = bx & (K_ - 1);
    int b = bx >> 6;
    int tid = threadIdx.x;
    int lane = tid & 63;
    int wv = tid >> 6;

    __shared__ float redF[4][128];
    __shared__ float redS[4];
    __shared__ int   redC[4];

    const int* Lb = L + b * S_;
    const float* Fb = F + (size_t)b * S_ * D_;

    float a0 = 0.f, a1 = 0.f, q0 = 0.f, q1 = 0.f;
    int cnt = 0;
    #pragma unroll
    for (int rr = 0; rr < 8; ++rr) {
        int r = (wv << 3) + rr;
        int lbl = Lb[(r << 6) + lane];
        unsigned long long m = __ballot(lbl == k);
        cnt += (int)__popcll(m);
        while (m) {               // wave-uniform trip count (~1 per round)
            int i = __ffsll((long long)m) - 1;
            m &= m - 1;
            const float* row = Fb + (size_t)((r << 6) + i) * D_;
            float v0 = row[lane];          // lane-indexed -> vector loads
            float v1 = row[64 + lane];
            a0 += v0; q0 = fmaf(v0, v0, q0);
            a1 += v1; q1 = fmaf(v1, v1, q1);
        }
    }
    float qq = q0 + q1;
    #pragma unroll
    for (int m = 1; m < 64; m <<= 1) qq += __shfl_xor(qq, m);
    redF[wv][lane] = a0;
    redF[wv][64 + lane] = a1;
    if (lane == 0) { redS[wv] = qq; redC[wv] = cnt; }
    __syncthreads();

    if (tid < 128) {
        float s = (redF[0][tid] + redF[1][tid]) + (redF[2][tid] + redF[3][tid]);
        fsumK[(size_t)bx * D_ + tid] = s;
    }
    if (tid == 0) {
        ssumK[bx] = (redS[0] + redS[1]) + (redS[2] + redS[3]);
        cntK[bx] = (float)(redC[0] + redC[1] + redC[2] + redC[3]);
    }
    if (b == 0 && wv == 0) {          // csqK[k], once
        float x0 = C[(k << 7) + lane];
        float x1 = C[(k << 7) + 64 + lane];
        float cs = fmaf(x0, x0, x1 * x1);
        #pragma unroll
        for (int m = 1; m < 64; m <<= 1) cs += __shfl_xor(cs, m);
        if (lane == 0) csqK[k] = cs;
    }
    if (blockIdx.x == 0 && tid < 17) AS(&cnts[tid * 16], 0);
}

// ---------------- K3: main per-anchor kernel + tree-counter final reduce
// grid = 512 blocks x 256 threads; each wave handles one octet (8 anchors)
__global__ void __launch_bounds__(256) k3_main(
    const float* __restrict__ F, const float* __restrict__ C,
    const float* __restrict__ phi, const int* __restrict__ L,
    const float* __restrict__ fsumK, const float* __restrict__ ssumK,
    const float* __restrict__ cntK, const float* __restrict__ csqK,
    float* __restrict__ partial, int* __restrict__ cnts,
    float* __restrict__ out) {

    __shared__ float Cs[K_ * 129];   // 129 stride: conflict-free b32 column reads
    __shared__ float4 redA[256];
    __shared__ float Fa[D_];
    __shared__ float wacc[4];
    __shared__ int isLast;
    int tid = threadIdx.x;
    int bxw = remap512(blockIdx.x);
    int b = bxw >> 6;

    // stage centroids: float4 global loads, scalar LDS stores into padded rows
    {
        const float4* C4 = (const float4*)C;
        #pragma unroll
        for (int it = 0; it < 8; ++it) {
            int i = it * 256 + tid;
            float4 v = C4[i];
            float* p = &Cs[(i >> 5) * 129 + ((i & 31) << 2)];
            p[0] = v.x; p[1] = v.y; p[2] = v.z; p[3] = v.w;
        }
    }
    // Fa[d] = sum_k fsumK[b,k,d]
    {
        int d4 = tid & 31, kg = tid >> 5;
        const float4* g4 = (const float4*)(fsumK + (size_t)b * K_ * D_) + (size_t)kg * 8 * 32 + d4;
        float4 s; s.x = s.y = s.z = s.w = 0.f;
        #pragma unroll
        for (int kk = 0; kk < 8; ++kk) {
            float4 v = g4[(size_t)kk * 32];
            s.x += v.x; s.y += v.y; s.z += v.z; s.w += v.w;
        }
        redA[tid] = s;
    }
    __syncthreads();
    if (tid < 32) {
        float4 a; a.x = a.y = a.z = a.w = 0.f;
        #pragma unroll
        for (int g = 0; g < 8; ++g) {
            float4 v = redA[g * 32 + tid];
            a.x += v.x; a.y += v.y; a.z += v.z; a.w += v.w;
        }
        ((float4*)Fa)[tid] = a;
    }
    __syncthreads();

    int lane = tid & 63;
    int wv = tid >> 6;

    float csq = csqK[lane];          // precomputed in k1
    float phv = phi[lane];
    float ssl = ssumK[b * K_ + lane];
    float cnl = cntK[b * K_ + lane];
    float ssA = ssl;
    #pragma unroll
    for (int m = 1; m < 64; m <<= 1) ssA += __shfl_xor(ssA, m);

    int wid = __builtin_amdgcn_readfirstlane(tid) >> 6;   // SGPR wave id
    int o = bxw * 4 + wid;
    int a0g = o * 8;
    const float4* F4 = (const float4*)F;

    // ---- phase A: per-anchor sq / dot(fsumK[lbl]) / dot(Fa); 8 lanes/anchor
    int j_of = lane >> 3, q = lane & 7;
    int a_mine = a0g + j_of;
    int lbl_p = L[a_mine];
    const float4* fr = F4 + (size_t)a_mine * 32;
    const float4* fk = (const float4*)(fsumK + (size_t)(b * K_ + lbl_p) * D_);
    const float4* fa4 = (const float4*)Fa;

    float sq_p = 0.f, dk_p = 0.f, da_p = 0.f;
    #pragma unroll
    for (int i = 0; i < 4; ++i) {
        int dq = i * 8 + q;
        float4 fv = fr[dq];
        float4 kv = fk[dq];
        float4 av = fa4[dq];
        sq_p = fmaf(fv.x, fv.x, fmaf(fv.y, fv.y, fmaf(fv.z, fv.z, fmaf(fv.w, fv.w, sq_p))));
        dk_p = fmaf(fv.x, kv.x, fmaf(fv.y, kv.y, fmaf(fv.z, kv.z, fmaf(fv.w, kv.w, dk_p))));
        da_p = fmaf(fv.x, av.x, fmaf(fv.y, av.y, fmaf(fv.z, av.z, fmaf(fv.w, av.w, da_p))));
    }
    #pragma unroll
    for (int m = 1; m < 8; m <<= 1) {
        sq_p += __shfl_xor(sq_p, m);
        dk_p += __shfl_xor(dk_p, m);
        da_p += __shfl_xor(da_p, m);
    }

    // ---- phase B: centroid dots, lane = k.
    // Force ONE base address into a VGPR pair so all 256 F loads become
    // global_load_dwordx4 with immediate offsets (j*512 + dq*16 <= 4080,
    // fits the 13-bit signed offset). vmcnt is in-order & pipelineable;
    // the ds_read (Cs) waits touch lgkmcnt only. No per-lane pointer
    // arrays, no fb[8] monolith -> no spill (R7's confound).
    const char* fbase = (const char*)(F4 + (size_t)a0g * 32);
    asm volatile("" : "+v"(fbase));

    float facc[8];
    #pragma unroll
    for (int j = 0; j < 8; ++j) facc[j] = 0.f;

    #pragma unroll 2
    for (int dq = 0; dq < 32; ++dq) {
        int cbase = lane * 129 + (dq << 2);
        float cv0 = Cs[cbase + 0];
        float cv1 = Cs[cbase + 1];
        float cv2 = Cs[cbase + 2];
        float cv3 = Cs[cbase + 3];
        float4 fb0[4];
        #pragma unroll
        for (int j = 0; j < 4; ++j)
            fb0[j] = *(const float4*)(fbase + j * 512 + dq * 16);
        #pragma unroll
        for (int j = 0; j < 4; ++j)
            facc[j] = fmaf(fb0[j].x, cv0, fmaf(fb0[j].y, cv1,
                      fmaf(fb0[j].z, cv2, fmaf(fb0[j].w, cv3, facc[j]))));
        float4 fb1[4];
        #pragma unroll
        for (int j = 0; j < 4; ++j)
            fb1[j] = *(const float4*)(fbase + (j + 4) * 512 + dq * 16);
        #pragma unroll
        for (int j = 0; j < 4; ++j)
            facc[j + 4] = fmaf(fb1[j].x, cv0, fmaf(fb1[j].y, cv1,
                          fmaf(fb1[j].z, cv2, fmaf(fb1[j].w, cv3, facc[j + 4]))));
    }

    // ---- phase C: per-anchor scalar epilogue
    float acc = 0.f;
    #pragma unroll
    for (int j = 0; j < 8; ++j) {
        float sq_j = __shfl(sq_p, j * 8);
        float dk_j = __shfl(dk_p, j * 8);
        float da_j = __shfl(da_p, j * 8);
        int lbl_j = __shfl(lbl_p, j * 8);
        float cnt_j = __shfl(cnl, lbl_j);
        float ssm_j = __shfl(ssl, lbl_j);

        float cd2 = (sq_j + csq - 2.f * facc[j]) * (1.f / D_);
        cd2 = fmaxf(cd2, 0.f) / phv;

        float s_cd = cd2;
        #pragma unroll
        for (int m = 1; m < 64; m <<= 1) s_cd += __shfl_xor(s_cd, m);
        float pos_cent = __shfl(cd2, lbl_j);

        float ncx = (s_cd - pos_cent) * (1.f / (K_ - 1));
        float S_same = (cnt_j * sq_j + ssm_j - 2.f * dk_j) * (1.f / D_);
        float S_all = ((float)S_ * sq_j + ssA - 2.f * da_j) * (1.f / D_);
        float pos_x = fmaxf(S_same, 0.f) / fmaxf(cnt_j - 1.f, 1.f);
        float neg_cnt = (float)S_ - cnt_j;
        float neg_x = fmaxf(S_all - S_same, 0.f) / fmaxf(neg_cnt, 1.f);

        float neg_sup = neg_x * __logf(neg_x + E_);
        float ncl = ncx * __logf(ncx + E_);

        float pa = SIG_ * pos_x + (1.f - SIG_) * pos_cent
                 - (SIG_ * neg_sup + (1.f - SIG_) * ncl) + EPS_;
        if (neg_cnt > 0.5f) acc += pa;
    }

    if (lane == 0) wacc[wid] = acc;
    __syncthreads();

    // ---- tree finish counter: 16 cacheline-spaced leaves + root
    if (tid == 0) {
        float blk = wacc[0] + wacc[1] + wacc[2] + wacc[3];
        AS(&partial[bxw], blk);
        int leaf = bxw & 15;
        int old = __hip_atomic_fetch_add(&cnts[leaf * 16], 1, __ATOMIC_ACQ_REL,
                                         __HIP_MEMORY_SCOPE_AGENT);
        int fin = 0;
        if (old == 32 - 1) {      // 512 blocks / 16 leaves
            int r = __hip_atomic_fetch_add(&cnts[256], 1, __ATOMIC_ACQ_REL,
                                           __HIP_MEMORY_SCOPE_AGENT);
            fin = (r == 15);
        }
        isLast = fin;
    }
    __syncthreads();
    if (isLast) {
        float v = 0.f;
        for (int i = tid; i < 512; i += 256) v += AL(&partial[i]);
        #pragma unroll
        for (int m = 1; m < 64; m <<= 1) v += __shfl_xor(v, m);
        if (lane == 0) wacc[wv] = v;
        __syncthreads();
        if (tid == 0) out[0] = (wacc[0] + wacc[1] + wacc[2] + wacc[3]) * (1.0f / (float)S_);
    }
}

extern "C" void kernel_launch(void* const* d_in, const int* in_sizes, int n_in,
                              void* d_out, int out_size, void* d_ws, size_t ws_size,
                              hipStream_t stream) {
    const float* F = (const float*)d_in[0];    // [B,S,D]
    const float* C = (const float*)d_in[1];    // [K,D]
    const float* phi = (const float*)d_in[2];  // [K]
    const int* L = (const int*)d_in[3];        // [B,S]
    float* out = (float*)d_out;

    float* ws = (float*)d_ws;
    float* fsumK = ws;                                // B*K*D = 65536
    float* ssumK = fsumK + (size_t)B_ * K_ * D_;      // 512
    float* cntK  = ssumK + B_ * K_;                   // 512
    float* csqK  = cntK + B_ * K_;                    // 64
    float* partial = csqK + K_;                       // 512
    int* cnts = (int*)(partial + 512);                // tree: 16 leaves*16 + root

    k1_stats<<<B_ * K_, 256, 0, stream>>>(F, C, L, fsumK, ssumK, cntK, csqK, cnts);
    k3_main<<<512, 256, 0, stream>>>(F, C, phi, L, fsumK, ssumK, cntK, csqK,
                                     partial, cnts, out);
}

// Round 10
// 38.154 us; speedup vs baseline: 7.2029x; 1.0284x over previous
//
#include <hip/hip_runtime.h>
#include <math.h>

#define B_ 8
#define S_ 2048
#define D_ 128
#define K_ 64
#define SIG_ 0.5f
#define EPS_ 10.0f
#define E_ 2.718281828459045f

// XCD-aware work remap (bijective on [0,512)): batch = bx&7 == XCD id.
__device__ __forceinline__ int remap512(int bx) { return ((bx & 7) << 6) | (bx >> 3); }

// broadcast one float from lane `src` (compile-time) to all lanes via v_readlane -> SGPR
__device__ __forceinline__ float bcast(float v, int src) {
    return __uint_as_float(__builtin_amdgcn_readlane(__float_as_uint(v), src));
}

// ---------------- K1: per (b,k) class stats, 4-wave ballot + immediate gather
// (identical to round 6's proven k1)
__global__ void __launch_bounds__(256) k1_stats(
    const float* __restrict__ F, const int* __restrict__ L,
    float* __restrict__ fsumK, float* __restrict__ ssumK, float* __restrict__ cntK,
    int* __restrict__ counter) {
    int bx = remap512(blockIdx.x);
    int k = bx & (K_ - 1);
    int b = bx >> 6;
    int tid = threadIdx.x;
    int lane = tid & 63;
    int wv = tid >> 6;

    __shared__ float redF[4][128];
    __shared__ float redS[4];
    __shared__ int   redC[4];

    const int* Lb = L + b * S_;
    const float* Fb = F + (size_t)b * S_ * D_;

    float a0 = 0.f, a1 = 0.f, q0 = 0.f, q1 = 0.f;
    int cnt = 0;
    #pragma unroll
    for (int rr = 0; rr < 8; ++rr) {
        int r = (wv << 3) + rr;
        int lbl = Lb[(r << 6) + lane];
        unsigned long long m = __ballot(lbl == k);
        cnt += (int)__popcll(m);
        while (m) {               // wave-uniform trip count (~1 per round)
            int i = __ffsll((long long)m) - 1;
            m &= m - 1;
            const float* row = Fb + (size_t)((r << 6) + i) * D_;
            float v0 = row[lane];          // lane-indexed -> vector loads
            float v1 = row[64 + lane];
            a0 += v0; q0 = fmaf(v0, v0, q0);
            a1 += v1; q1 = fmaf(v1, v1, q1);
        }
    }
    float qq = q0 + q1;
    #pragma unroll
    for (int m = 1; m < 64; m <<= 1) qq += __shfl_xor(qq, m);
    redF[wv][lane] = a0;
    redF[wv][64 + lane] = a1;
    if (lane == 0) { redS[wv] = qq; redC[wv] = cnt; }
    __syncthreads();

    if (tid < 128) {
        float s = (redF[0][tid] + redF[1][tid]) + (redF[2][tid] + redF[3][tid]);
        fsumK[(size_t)bx * D_ + tid] = s;
    }
    if (tid == 0) {
        ssumK[bx] = (redS[0] + redS[1]) + (redS[2] + redS[3]);
        cntK[bx] = (float)(redC[0] + redC[1] + redC[2] + redC[3]);
        if (bx == 0) *counter = 0;   // stream-ordered init for k3's last-block reduce
    }
}

// ---------------- K3: main per-anchor kernel + last-block final reduce
// grid = 512 blocks x 256 threads; each wave handles one octet (8 anchors).
// Phase B reads F from REGISTERS via v_readlane broadcast (no s_load, no K$).
__global__ void __launch_bounds__(256) k3_main(
    const float* __restrict__ F, const float* __restrict__ C,
    const float* __restrict__ phi, const int* __restrict__ L,
    const float* __restrict__ fsumK, const float* __restrict__ ssumK,
    const float* __restrict__ cntK, float* __restrict__ partial,
    int* __restrict__ counter, float* __restrict__ out) {

    __shared__ float Cs[K_ * 129];   // 129 stride: conflict-free b32 column reads
    __shared__ float4 redA[256];
    __shared__ float Fa[D_];
    __shared__ float wacc[4];
    __shared__ int isLast;
    int tid = threadIdx.x;
    int bxw = remap512(blockIdx.x);
    int b = bxw >> 6;

    // stage centroids: float4 global loads, scalar LDS stores into padded rows
    {
        const float4* C4 = (const float4*)C;
        #pragma unroll
        for (int it = 0; it < 8; ++it) {
            int i = it * 256 + tid;
            float4 v = C4[i];
            float* p = &Cs[(i >> 5) * 129 + ((i & 31) << 2)];
            p[0] = v.x; p[1] = v.y; p[2] = v.z; p[3] = v.w;
        }
    }
    // Fa[d] = sum_k fsumK[b,k,d]
    {
        int d4 = tid & 31, kg = tid >> 5;
        const float4* g4 = (const float4*)(fsumK + (size_t)b * K_ * D_) + (size_t)kg * 8 * 32 + d4;
        float4 s; s.x = s.y = s.z = s.w = 0.f;
        #pragma unroll
        for (int kk = 0; kk < 8; ++kk) {
            float4 v = g4[(size_t)kk * 32];
            s.x += v.x; s.y += v.y; s.z += v.z; s.w += v.w;
        }
        redA[tid] = s;
    }
    __syncthreads();
    if (tid < 32) {
        float4 a; a.x = a.y = a.z = a.w = 0.f;
        #pragma unroll
        for (int g = 0; g < 8; ++g) {
            float4 v = redA[g * 32 + tid];
            a.x += v.x; a.y += v.y; a.z += v.z; a.w += v.w;
        }
        ((float4*)Fa)[tid] = a;
    }
    __syncthreads();

    int lane = tid & 63;
    int wv = tid >> 6;

    float c0 = 0.f, c1 = 0.f, c2 = 0.f, c3 = 0.f;
    #pragma unroll
    for (int dd = 0; dd < D_; dd += 4) {
        c0 = fmaf(Cs[lane * 129 + dd + 0], Cs[lane * 129 + dd + 0], c0);
        c1 = fmaf(Cs[lane * 129 + dd + 1], Cs[lane * 129 + dd + 1], c1);
        c2 = fmaf(Cs[lane * 129 + dd + 2], Cs[lane * 129 + dd + 2], c2);
        c3 = fmaf(Cs[lane * 129 + dd + 3], Cs[lane * 129 + dd + 3], c3);
    }
    float csq = (c0 + c1) + (c2 + c3);
    float phv = phi[lane];
    float ssl = ssumK[b * K_ + lane];
    float cnl = cntK[b * K_ + lane];
    float ssA = ssl;
    #pragma unroll
    for (int m = 1; m < 64; m <<= 1) ssA += __shfl_xor(ssA, m);

    int wid = __builtin_amdgcn_readfirstlane(tid) >> 6;   // SGPR wave id
    int o = bxw * 4 + wid;
    int a0g = o * 8;
    const float4* F4 = (const float4*)F;

    // ---- phase A: load my 16 F floats (kept for phase B!), sq/dk/da dots
    int j_of = lane >> 3, q = lane & 7;
    int a_mine = a0g + j_of;
    int lbl_p = L[a_mine];
    const float4* fr = F4 + (size_t)a_mine * 32;
    const float4* fk = (const float4*)(fsumK + (size_t)(b * K_ + lbl_p) * D_);
    const float4* fa4 = (const float4*)Fa;

    float4 fv0 = fr[q];
    float4 fv1 = fr[8 + q];
    float4 fv2 = fr[16 + q];
    float4 fv3 = fr[24 + q];

    float sq_p, dk_p, da_p;
    {
        float4 kv0 = fk[q], kv1 = fk[8 + q], kv2 = fk[16 + q], kv3 = fk[24 + q];
        float4 av0 = fa4[q], av1 = fa4[8 + q], av2 = fa4[16 + q], av3 = fa4[24 + q];
        sq_p =
            fmaf(fv0.x, fv0.x, fmaf(fv0.y, fv0.y, fmaf(fv0.z, fv0.z, fv0.w * fv0.w))) +
            fmaf(fv1.x, fv1.x, fmaf(fv1.y, fv1.y, fmaf(fv1.z, fv1.z, fv1.w * fv1.w))) +
            fmaf(fv2.x, fv2.x, fmaf(fv2.y, fv2.y, fmaf(fv2.z, fv2.z, fv2.w * fv2.w))) +
            fmaf(fv3.x, fv3.x, fmaf(fv3.y, fv3.y, fmaf(fv3.z, fv3.z, fv3.w * fv3.w)));
        dk_p =
            fmaf(fv0.x, kv0.x, fmaf(fv0.y, kv0.y, fmaf(fv0.z, kv0.z, fv0.w * kv0.w))) +
            fmaf(fv1.x, kv1.x, fmaf(fv1.y, kv1.y, fmaf(fv1.z, kv1.z, fv1.w * kv1.w))) +
            fmaf(fv2.x, kv2.x, fmaf(fv2.y, kv2.y, fmaf(fv2.z, kv2.z, fv2.w * kv2.w))) +
            fmaf(fv3.x, kv3.x, fmaf(fv3.y, kv3.y, fmaf(fv3.z, kv3.z, fv3.w * kv3.w)));
        da_p =
            fmaf(fv0.x, av0.x, fmaf(fv0.y, av0.y, fmaf(fv0.z, av0.z, fv0.w * av0.w))) +
            fmaf(fv1.x, av1.x, fmaf(fv1.y, av1.y, fmaf(fv1.z, av1.z, fv1.w * av1.w))) +
            fmaf(fv2.x, av2.x, fmaf(fv2.y, av2.y, fmaf(fv2.z, av2.z, fv2.w * av2.w))) +
            fmaf(fv3.x, av3.x, fmaf(fv3.y, av3.y, fmaf(fv3.z, av3.z, fv3.w * av3.w)));
    }
    #pragma unroll
    for (int m = 1; m < 8; m <<= 1) {
        sq_p += __shfl_xor(sq_p, m);
        dk_p += __shfl_xor(dk_p, m);
        da_p += __shfl_xor(da_p, m);
    }

    // ---- phase B: centroid dots, lane = k. F comes from WAVE REGISTERS:
    // float4 #dq of anchor j lives in lane j*8+(dq&7), register fv_{dq>>3}.
    // v_readlane (compile-time lane) -> SGPR feeds v_fmac's SGPR slot.
    // No global/SMEM access at all; Cs reads are conflict-free b32.
    float facc[8];
    #pragma unroll
    for (int j = 0; j < 8; ++j) facc[j] = 0.f;

    #pragma unroll
    for (int dq = 0; dq < 32; ++dq) {
        int cbase = lane * 129 + (dq << 2);
        float cv0 = Cs[cbase + 0];
        float cv1 = Cs[cbase + 1];
        float cv2 = Cs[cbase + 2];
        float cv3 = Cs[cbase + 3];
        float4 fvi = (dq < 8) ? fv0 : (dq < 16) ? fv1 : (dq < 24) ? fv2 : fv3;
        #pragma unroll
        for (int j = 0; j < 8; ++j) {
            int src = j * 8 + (dq & 7);          // compile-time constant
            float fx = bcast(fvi.x, src);
            float fy = bcast(fvi.y, src);
            float fz = bcast(fvi.z, src);
            float fw = bcast(fvi.w, src);
            facc[j] = fmaf(fx, cv0, fmaf(fy, cv1,
                      fmaf(fz, cv2, fmaf(fw, cv3, facc[j]))));
        }
    }

    // ---- phase C: per-anchor scalar epilogue
    float acc = 0.f;
    #pragma unroll
    for (int j = 0; j < 8; ++j) {
        float sq_j = __shfl(sq_p, j * 8);
        float dk_j = __shfl(dk_p, j * 8);
        float da_j = __shfl(da_p, j * 8);
        int lbl_j = __shfl(lbl_p, j * 8);
        float cnt_j = __shfl(cnl, lbl_j);
        float ssm_j = __shfl(ssl, lbl_j);

        float cd2 = (sq_j + csq - 2.f * facc[j]) * (1.f / D_);
        cd2 = fmaxf(cd2, 0.f) / phv;

        float s_cd = cd2;
        #pragma unroll
        for (int m = 1; m < 64; m <<= 1) s_cd += __shfl_xor(s_cd, m);
        float pos_cent = __shfl(cd2, lbl_j);

        float ncx = (s_cd - pos_cent) * (1.f / (K_ - 1));
        float S_same = (cnt_j * sq_j + ssm_j - 2.f * dk_j) * (1.f / D_);
        float S_all = ((float)S_ * sq_j + ssA - 2.f * da_j) * (1.f / D_);
        float pos_x = fmaxf(S_same, 0.f) / fmaxf(cnt_j - 1.f, 1.f);
        float neg_cnt = (float)S_ - cnt_j;
        float neg_x = fmaxf(S_all - S_same, 0.f) / fmaxf(neg_cnt, 1.f);

        float neg_sup = neg_x * __logf(neg_x + E_);
        float ncl = ncx * __logf(ncx + E_);

        float pa = SIG_ * pos_x + (1.f - SIG_) * pos_cent
                 - (SIG_ * neg_sup + (1.f - SIG_) * ncl) + EPS_;
        if (neg_cnt > 0.5f) acc += pa;
    }

    if (lane == 0) wacc[wid] = acc;
    __syncthreads();

    // ---- last-block final reduce (agent-scope atomics; proven)
    if (tid == 0) {
        float blk = wacc[0] + wacc[1] + wacc[2] + wacc[3];
        __hip_atomic_store(&partial[bxw], blk, __ATOMIC_RELAXED,
                           __HIP_MEMORY_SCOPE_AGENT);
        int old = __hip_atomic_fetch_add(counter, 1, __ATOMIC_ACQ_REL,
                                         __HIP_MEMORY_SCOPE_AGENT);
        isLast = (old == (int)gridDim.x - 1) ? 1 : 0;
    }
    __syncthreads();
    if (isLast) {
        float v = 0.f;
        for (int i = tid; i < 512; i += 256) {
            v += __hip_atomic_load(&partial[i], __ATOMIC_RELAXED,
                                   __HIP_MEMORY_SCOPE_AGENT);
        }
        #pragma unroll
        for (int m = 1; m < 64; m <<= 1) v += __shfl_xor(v, m);
        if (lane == 0) wacc[wv] = v;
        __syncthreads();
        if (tid == 0) out[0] = (wacc[0] + wacc[1] + wacc[2] + wacc[3]) * (1.0f / (float)S_);
    }
}

extern "C" void kernel_launch(void* const* d_in, const int* in_sizes, int n_in,
                              void* d_out, int out_size, void* d_ws, size_t ws_size,
                              hipStream_t stream) {
    const float* F = (const float*)d_in[0];    // [B,S,D]
    const float* C = (const float*)d_in[1];    // [K,D]
    const float* phi = (const float*)d_in[2];  // [K]
    const int* L = (const int*)d_in[3];        // [B,S]
    float* out = (float*)d_out;

    float* ws = (float*)d_ws;
    float* fsumK = ws;                                // B*K*D = 65536
    float* ssumK = fsumK + (size_t)B_ * K_ * D_;      // 512
    float* cntK  = ssumK + B_ * K_;                   // 512
    float* partial = cntK + B_ * K_;                  // 512
    int* counter = (int*)(partial + 512);             // 1

    k1_stats<<<B_ * K_, 256, 0, stream>>>(F, L, fsumK, ssumK, cntK, counter);
    k3_main<<<512, 256, 0, stream>>>(F, C, phi, L, fsumK, ssumK, cntK, partial, counter, out);
}